// Round 15
// baseline (384.893 us; speedup 1.0000x reference)
//
#include <hip/hip_runtime.h>

// OT_GNN_layer — round 15: f-split dot phase (4x fewer DS reads) + fused
// Sinkhorn (validated R13/R14). N,F,T,Tn,C = 10000,128,16,8,8 ; E=160000.
// R14 evidence: phase-1's 544 ds_read_b128/lane serialized on the DS pipe
// (~12cyc each x 39 waves/CU ~= the 126us marginal cost; VALUBusy fell to
// 69%). Fix: quad lane p processes chunks {p+4ci} and accumulates ALL 4
// column-pairs of its template, then quad-allreduce + select own pair.
// DS reads/lane: 544 -> 136 (stride-4 chunks = conflict-free vs stride-132).

#define F_DIM 128
#define KN 16
#define NL 17
#define TT 16
#define TN 8
#define N_NODES 10000
#define E_EDGES 160000
#define CEXP 7.2134752044448170f    // (1/EPS)*log2(e), EPS=0.2
#define ICEXP 0.138629436111989062f // 1/CEXP

// ws float offsets
#define WS_TFSQ 0
#define WS_CC 128
#define WS_C2 256
#define WS_TFT 1280   // tftp[c*512 + pair*8 + k*2 + par], 16384 floats

typedef float v2f __attribute__((ext_vector_type(2)));

template <int CTRL>
__device__ __forceinline__ float dppmov(float x) {
  return __int_as_float(__builtin_amdgcn_update_dpp(
      0, __float_as_int(x), CTRL, 0xF, 0xF, true));
}
__device__ __forceinline__ float q4sum(float x) {
  x += dppmov<0xB1>(x);
  x += dppmov<0x4E>(x);
  return x;
}
__device__ __forceinline__ float q4min(float x) {
  x = fminf(x, dppmov<0xB1>(x));
  x = fminf(x, dppmov<0x4E>(x));
  return x;
}
__device__ __forceinline__ v2f q4sumv(v2f a) {
  a.x = q4sum(a.x);
  a.y = q4sum(a.y);
  return a;
}
__device__ __forceinline__ v2f exp2v(v2f a) {
  v2f r; r.x = exp2f(a.x); r.y = exp2f(a.y); return r;
}
__device__ __forceinline__ v2f rcpv(v2f a) {
  v2f r;
  r.x = __builtin_amdgcn_rcpf(a.x);
  r.y = __builtin_amdgcn_rcpf(a.y);
  return r;
}
__device__ __forceinline__ v2f minv(v2f a, v2f b) {
  v2f r; r.x = fminf(a.x, b.x); r.y = fminf(a.y, b.y); return r;
}

// batched reciprocal of 17 positive values: 4 rcp + ~39 mul (validated R11)
__device__ __forceinline__ void minv17(const float r[NL], float U[NL]) {
  {
    float p1 = r[0] * r[1], p2 = p1 * r[2], p3 = p2 * r[3];
    float R = __builtin_amdgcn_rcpf(p3);
    U[3] = R * p2; R *= r[3];
    U[2] = R * p1; R *= r[2];
    U[1] = R * r[0];
    U[0] = R * r[1];
  }
  {
    float p1 = r[4] * r[5], p2 = p1 * r[6], p3 = p2 * r[7];
    float R = __builtin_amdgcn_rcpf(p3);
    U[7] = R * p2; R *= r[7];
    U[6] = R * p1; R *= r[6];
    U[5] = R * r[4];
    U[4] = R * r[5];
  }
  {
    float p1 = r[8] * r[9], p2 = p1 * r[10], p3 = p2 * r[11];
    float R = __builtin_amdgcn_rcpf(p3);
    U[11] = R * p2; R *= r[11];
    U[10] = R * p1; R *= r[10];
    U[9] = R * r[8];
    U[8] = R * r[9];
  }
  {
    float p1 = r[12] * r[13], p2 = p1 * r[14], p3 = p2 * r[15],
          p4 = p3 * r[16];
    float R = __builtin_amdgcn_rcpf(p4);
    U[16] = R * p3; R *= r[16];
    U[15] = R * p2; R *= r[15];
    U[14] = R * p1; R *= r[14];
    U[13] = R * r[12];
    U[12] = R * r[13];
  }
}

// f-split partial-dot pass over rows [R0, R0+NR): lane (t,p) covers chunks
// {p+4ci}, accumulates all 4 pairs of template t, quad-allreduces, keeps own.
template <int R0, int NR>
__device__ __forceinline__ void dot_pass(
    const float (*xrow)[132], const float* __restrict__ tftp,
    int t, int p, v2f* d) {
  v2f acc[NR][4];
#pragma unroll
  for (int j = 0; j < NR; ++j)
#pragma unroll
    for (int q = 0; q < 4; ++q) acc[j][q] = (v2f){0.f, 0.f};

#pragma unroll
  for (int ci = 0; ci < 8; ++ci) {
    const int c = p + 4 * ci;  // stride-4: conflict-free vs 132-stride rows
    const float* tb = tftp + c * 512 + t * 32;  // 4 pairs x [k][par], 128B
    float4 tq[8];
#pragma unroll
    for (int j2 = 0; j2 < 8; ++j2) tq[j2] = *(const float4*)(tb + j2 * 4);
#pragma unroll
    for (int j = 0; j < NR; ++j) {
      float4 xv = *(const float4*)&xrow[R0 + j][c * 4];
#pragma unroll
      for (int q = 0; q < 4; ++q) {
        v2f k0 = {tq[2 * q].x, tq[2 * q].y};
        v2f k1 = {tq[2 * q].z, tq[2 * q].w};
        v2f k2 = {tq[2 * q + 1].x, tq[2 * q + 1].y};
        v2f k3 = {tq[2 * q + 1].z, tq[2 * q + 1].w};
        acc[j][q] += (v2f){xv.x, xv.x} * k0;
        acc[j][q] += (v2f){xv.y, xv.y} * k1;
        acc[j][q] += (v2f){xv.z, xv.z} * k2;
        acc[j][q] += (v2f){xv.w, xv.w} * k3;
      }
    }
  }
#pragma unroll
  for (int j = 0; j < NR; ++j) {
#pragma unroll
    for (int q = 0; q < 4; ++q) acc[j][q] = q4sumv(acc[j][q]);
    v2f r0 = (p & 2) ? acc[j][2] : acc[j][0];
    v2f r1 = (p & 2) ? acc[j][3] : acc[j][1];
    d[R0 + j] = (p & 1) ? r1 : r0;
  }
}

// ---------------- setup: tables + pair-transposed TF (validated R14) --------
__global__ __launch_bounds__(256) void setup_kernel(
    const float* __restrict__ L, const float* __restrict__ TF,
    float* __restrict__ ws) {
  const int tid = threadIdx.x;
  if (tid < 128) {
    const int t = tid >> 3, r = tid & 7;
    float q = 0.f;
#pragma unroll
    for (int mm = 0; mm < TN; ++mm) {
      float val = 0.5f * (L[t * 64 + r * 8 + mm] + L[t * 64 + mm * 8 + r]);
      ws[WS_C2 + t * 64 + r * 8 + mm] = val;
      q += val * val;
    }
    ws[WS_CC + tid] = 0.125f * q;
  } else {
    const int row = tid - 128;
    const float4* tf = (const float4*)(TF + (size_t)row * F_DIM);
    float s = 0.f;
#pragma unroll
    for (int c = 0; c < 32; ++c) {
      float4 v = tf[c];
      s += v.x * v.x + v.y * v.y + v.z * v.z + v.w * v.w;
    }
    ws[WS_TFSQ + row] = s;
  }
  for (int i = tid; i < 16384; i += 256) {
    int c = i >> 9, rem = i & 511;
    int pair = rem >> 3, k = (rem >> 1) & 3, par = i & 1;
    ws[WS_TFT + i] = TF[(size_t)(pair * 2 + par) * F_DIM + c * 4 + k];
  }
}

// ---------------- fused: f-split dots -> Sinkhorn -> head ----------------
__global__ __launch_bounds__(256) void fgw_fused_kernel(
    const float* __restrict__ x, const int* __restrict__ edge,
    const float* __restrict__ ws, const float* __restrict__ W,
    const float* __restrict__ bias, float* __restrict__ out) {
  __shared__ float xls[4][NL][132];
  __shared__ float xsqs[4][NL];
  __shared__ int nas[4][NL];
  __shared__ float C2s[TT * 68];
  __shared__ float sc[4][TT * 20];
  __shared__ float fgw_s[4][TT];

  const int tid = threadIdx.x;
  const int node0 = blockIdx.x * 4;
  const int* dst = edge + E_EDGES;

  for (int i = tid; i < 1024; i += 256) {
    int t = i >> 6, rest = i & 63;
    C2s[t * 68 + rest] = ws[WS_C2 + i];
  }
  if (tid < 4 * NL) {
    int nl = tid / NL, a = tid - nl * NL;
    int nd = node0 + nl;
    nas[nl][a] = (a == 0) ? nd : dst[nd * KN + a - 1];
  }
  __syncthreads();

  for (int i = tid; i < 4 * NL * 32; i += 256) {
    int nl = i / (NL * 32);
    int ii = i - nl * (NL * 32);
    int row = ii >> 5, c4 = ii & 31;
    float4 v = ((const float4*)(x + (size_t)nas[nl][row] * F_DIM))[c4];
    *(float4*)&xls[nl][row][c4 * 4] = v;
  }
  __syncthreads();

  if (tid < 4 * NL) {
    int nl = tid / NL, a = tid - nl * NL;
    v2f xq = {0.f, 0.f};
#pragma unroll
    for (int c = 0; c < 32; ++c) {
      float4 xv = *(const float4*)&xls[nl][a][c * 4];
      v2f xa = {xv.x, xv.y}, xb = {xv.z, xv.w};
      xq = xa * xa + xq;
      xq = xb * xb + xq;
    }
    xsqs[nl][a] = xq.x + xq.y;
  }
  __syncthreads();

  const int lane = tid & 63;
  const int w = tid >> 6;
  const int node = node0 + w;
  const int t = lane >> 2;   // template
  const int p = lane & 3;    // column pair: m = {2p, 2p+1}

  // ---- phase 1: f-split dots (two row passes; d[a] = lane's pair dots) ----
  v2f d[NL];
  const float* tftp = ws + WS_TFT;
  dot_pass<0, 9>(xls[w], tftp, t, p, d);
  dot_pass<9, 8>(xls[w], tftp, t, p, d);

  // ---- Mh (v2f, regs) -> EM2 (validated R14) ----
  const v2f tfsq2 = *(const v2f*)(ws + WS_TFSQ + 2 * lane);
  const v2f cc2 = *(const v2f*)(ws + WS_CC + 2 * lane);
  const v2f b0 = 0.5f * ((v2f){16.f / 17.f, 16.f / 17.f} + cc2);
  const v2f ba = 0.5f * ((v2f){1.f / 17.f, 1.f / 17.f} + cc2);

  v2f EM2[NL], Mh02, mnr;
  {
    v2f m0 = (xsqs[w][0] + tfsq2 - 2.f * d[0]) * (1.f / 256.f) + b0;
    Mh02 = m0;
    EM2[0] = exp2v(-m0 * CEXP);
    v2f m1 = (xsqs[w][1] + tfsq2 - 2.f * d[1]) * (1.f / 256.f) + ba;
    mnr = m1;
    EM2[1] = exp2v(-m1 * CEXP);
#pragma unroll
    for (int a = 2; a < NL; ++a) {
      v2f mv = (xsqs[w][a] + tfsq2 - 2.f * d[a]) * (1.f / 256.f) + ba;
      mnr = minv(mnr, mv);
      EM2[a] = exp2v(-mv * CEXP);
    }
  }

  // ---- phase 2: Sinkhorn (byte-identical validated R13/R14) ----
  v2f PK2[NL];
#pragma unroll
  for (int a = 0; a < NL; ++a) PK2[a] = (v2f){1.f / 136.f, 1.f / 136.f};

  float r[NL], U[NL];
  float* myc = &sc[w][t * 20];
  v2f A02, A12;

#pragma unroll 1
  for (int it = 0; it < 5; ++it) {
    v2f sP2 = PK2[1];
#pragma unroll
    for (int a = 2; a < NL; ++a) sP2 += PK2[a];
    *(v2f*)&myc[2 * p] = sP2;
    *(v2f*)&myc[8 + 2 * p] = PK2[0];
    float4 s01 = *(const float4*)&myc[0];
    float4 s23 = *(const float4*)&myc[4];
    float4 p01 = *(const float4*)&myc[8];
    float4 p23 = *(const float4*)&myc[12];
    {
      const float* c2b = &C2s[t * 68 + 2 * p];
      v2f c0 = *(const v2f*)(c2b), c1 = *(const v2f*)(c2b + 8),
          c2 = *(const v2f*)(c2b + 16), c3 = *(const v2f*)(c2b + 24),
          c4 = *(const v2f*)(c2b + 32), c5 = *(const v2f*)(c2b + 40),
          c6 = *(const v2f*)(c2b + 48), c7 = *(const v2f*)(c2b + 56);
      A02 = c0 * s01.x + c1 * s01.y;
      A02 += c2 * s01.z + c3 * s01.w;
      A02 += c4 * s23.x + c5 * s23.y;
      A02 += c6 * s23.z + c7 * s23.w;
      A12 = c0 * p01.x + c1 * p01.y;
      A12 += c2 * p01.z + c3 * p01.w;
      A12 += c4 * p23.x + c5 * p23.y;
      A12 += c6 * p23.z + c7 * p23.w;
    }

    v2f g0 = Mh02 - A02, g1 = mnr - A12;
    float gmin = fminf(fminf(g0.x, g0.y), fminf(g1.x, g1.y));
    gmin = q4min(gmin);

    v2f EA0 = exp2v((A02 + gmin) * CEXP);
    v2f EA1 = exp2v((A12 + gmin) * CEXP);
    PK2[0] = PK2[0] * EM2[0] * EA0;
#pragma unroll
    for (int a = 1; a < NL; ++a) PK2[a] = PK2[a] * EM2[a] * EA1;

    v2f V;
    {
#pragma unroll
      for (int a = 0; a < NL; ++a) {
        float rr = PK2[a].x + PK2[a].y;
        r[a] = q4sum(rr);
      }
      minv17(r, U);
      v2f s2 = PK2[0] * U[0];
#pragma unroll
      for (int a = 1; a < NL; ++a) s2 += PK2[a] * U[a];
      V = 2.125f * rcpv(s2);
    }
#pragma unroll 1
    for (int si = 1; si < 10; ++si) {
#pragma unroll
      for (int a = 0; a < NL; ++a) {
        v2f pr = PK2[a] * V;
        r[a] = q4sum(pr.x + pr.y);
      }
      minv17(r, U);
      v2f s2 = PK2[0] * U[0];
#pragma unroll
      for (int a = 1; a < NL; ++a) s2 += PK2[a] * U[a];
      V = 2.125f * rcpv(s2);
    }
    const v2f hV = V * (1.f / 17.f);
#pragma unroll
    for (int a = 0; a < NL; ++a) PK2[a] = PK2[a] * U[a] * hV;
  }

  // ---- final fgw ----
  {
    v2f sP2 = PK2[1];
#pragma unroll
    for (int a = 2; a < NL; ++a) sP2 += PK2[a];
    *(v2f*)&myc[2 * p] = sP2;
    *(v2f*)&myc[8 + 2 * p] = PK2[0];
    float4 s01 = *(const float4*)&myc[0];
    float4 s23 = *(const float4*)&myc[4];
    float4 p01 = *(const float4*)&myc[8];
    float4 p23 = *(const float4*)&myc[12];
    const float* c2b = &C2s[t * 68 + 2 * p];
    v2f c0 = *(const v2f*)(c2b), c1 = *(const v2f*)(c2b + 8),
        c2 = *(const v2f*)(c2b + 16), c3 = *(const v2f*)(c2b + 24),
        c4 = *(const v2f*)(c2b + 32), c5 = *(const v2f*)(c2b + 40),
        c6 = *(const v2f*)(c2b + 48), c7 = *(const v2f*)(c2b + 56);
    A02 = c0 * s01.x + c1 * s01.y;
    A02 += c2 * s01.z + c3 * s01.w;
    A02 += c4 * s23.x + c5 * s23.y;
    A02 += c6 * s23.z + c7 * s23.w;
    A12 = c0 * p01.x + c1 * p01.y;
    A12 += c2 * p01.z + c3 * p01.w;
    A12 += c4 * p23.x + c5 * p23.y;
    A12 += c6 * p23.z + c7 * p23.w;
  }
  v2f acc2 = {0.f, 0.f};
#pragma unroll
  for (int a = 0; a < NL; ++a) {
    v2f mh2;
    mh2.x = -__log2f(EM2[a].x) * ICEXP;
    mh2.y = -__log2f(EM2[a].y) * ICEXP;
    acc2 += (mh2 - ((a == 0) ? A02 : A12)) * PK2[a];
  }
  float acc = q4sum(acc2.x + acc2.y);  // fgw(node,t), replicated in quad

  if (p == 0) fgw_s[w][t] = acc;
  // intra-wave LDS RAW: program order within a wave (validated R13/R14)
  if (lane < 8) {
    float o = bias[lane];
#pragma unroll
    for (int t2 = 0; t2 < TT; ++t2) o += fgw_s[w][t2] * W[t2 * 8 + lane];
    out[node * 8 + lane] = o;
  }
}

extern "C" void kernel_launch(void* const* d_in, const int* in_sizes, int n_in,
                              void* d_out, int out_size, void* d_ws, size_t ws_size,
                              hipStream_t stream) {
  const float* x = (const float*)d_in[0];
  const int* edge = (const int*)d_in[1];
  const float* L = (const float*)d_in[2];
  const float* TF = (const float*)d_in[3];
  const float* W = (const float*)d_in[4];
  const float* bias = (const float*)d_in[5];
  float* out = (float*)d_out;
  float* ws = (float*)d_ws;
  (void)in_sizes; (void)n_in; (void)ws_size; (void)out_size;

  setup_kernel<<<1, 256, 0, stream>>>(L, TF, ws);
  fgw_fused_kernel<<<N_NODES / 4, 256, 0, stream>>>(x, edge, ws, W, bias,
                                                    out);
}

// Round 16
// 250.907 us; speedup vs baseline: 1.5340x; 1.5340x over previous
//
#include <hip/hip_runtime.h>

// OT_GNN_layer — round 16: G2 precompute kills the 17x-redundant dot work.
// N,F,T,Tn,C = 10000,128,16,8,8 ; E=160000 ; planar edge; hardcoded.
// R14/R15 lesson: recomputing per-node dots costs DS pipe (544 reads) or
// VGPRs (f-split -> 132 regs, occupancy collapse). Instead:
//   gemm_g2: G2[n][tm] = (|x_n|^2 - 2 x_n.TF_tm)/256  (10000x128, L2-resident
//            5.12MB; 0.65 GFLOP).
//   sink:    per-wave G2-row gather (17 coalesced 512B L2 reads -> LDS),
//            Mh[a] = g2pair + (tfsq/256 + base) = 17 ds_read_b64 + 17 pk_add.
//            Sinkhorn phase byte-identical to validated R13/R14.

#define F_DIM 128
#define KN 16
#define NL 17
#define TT 16
#define TN 8
#define N_NODES 10000
#define E_EDGES 160000
#define CEXP 7.2134752044448170f    // (1/EPS)*log2(e), EPS=0.2
#define ICEXP 0.138629436111989062f // 1/CEXP

// ws float offsets
#define WS_TFSQ 0
#define WS_CC 128
#define WS_C2 256
#define WS_TFT 1280               // float4 tft[c*128+row], 4096 entries
#define WS_G2 17664               // 10000*128 floats = 5.12 MB

typedef float v2f __attribute__((ext_vector_type(2)));

template <int CTRL>
__device__ __forceinline__ float dppmov(float x) {
  return __int_as_float(__builtin_amdgcn_update_dpp(
      0, __float_as_int(x), CTRL, 0xF, 0xF, true));
}
__device__ __forceinline__ float q4sum(float x) {
  x += dppmov<0xB1>(x);
  x += dppmov<0x4E>(x);
  return x;
}
__device__ __forceinline__ float q4min(float x) {
  x = fminf(x, dppmov<0xB1>(x));
  x = fminf(x, dppmov<0x4E>(x));
  return x;
}
__device__ __forceinline__ v2f exp2v(v2f a) {
  v2f r; r.x = exp2f(a.x); r.y = exp2f(a.y); return r;
}
__device__ __forceinline__ v2f rcpv(v2f a) {
  v2f r;
  r.x = __builtin_amdgcn_rcpf(a.x);
  r.y = __builtin_amdgcn_rcpf(a.y);
  return r;
}
__device__ __forceinline__ v2f minv(v2f a, v2f b) {
  v2f r; r.x = fminf(a.x, b.x); r.y = fminf(a.y, b.y); return r;
}

// batched reciprocal of 17 positive values: 4 rcp + ~39 mul (validated R11)
__device__ __forceinline__ void minv17(const float r[NL], float U[NL]) {
  {
    float p1 = r[0] * r[1], p2 = p1 * r[2], p3 = p2 * r[3];
    float R = __builtin_amdgcn_rcpf(p3);
    U[3] = R * p2; R *= r[3];
    U[2] = R * p1; R *= r[2];
    U[1] = R * r[0];
    U[0] = R * r[1];
  }
  {
    float p1 = r[4] * r[5], p2 = p1 * r[6], p3 = p2 * r[7];
    float R = __builtin_amdgcn_rcpf(p3);
    U[7] = R * p2; R *= r[7];
    U[6] = R * p1; R *= r[6];
    U[5] = R * r[4];
    U[4] = R * r[5];
  }
  {
    float p1 = r[8] * r[9], p2 = p1 * r[10], p3 = p2 * r[11];
    float R = __builtin_amdgcn_rcpf(p3);
    U[11] = R * p2; R *= r[11];
    U[10] = R * p1; R *= r[10];
    U[9] = R * r[8];
    U[8] = R * r[9];
  }
  {
    float p1 = r[12] * r[13], p2 = p1 * r[14], p3 = p2 * r[15],
          p4 = p3 * r[16];
    float R = __builtin_amdgcn_rcpf(p4);
    U[16] = R * p3; R *= r[16];
    U[15] = R * p2; R *= r[15];
    U[14] = R * p1; R *= r[14];
    U[13] = R * r[12];
    U[12] = R * r[13];
  }
}

// ---------------- setup: tables + col-major TF (validated R12) ----------------
__global__ __launch_bounds__(256) void setup_kernel(
    const float* __restrict__ L, const float* __restrict__ TF,
    float* __restrict__ ws) {
  const int tid = threadIdx.x;
  if (tid < 128) {
    const int t = tid >> 3, r = tid & 7;
    float q = 0.f;
#pragma unroll
    for (int mm = 0; mm < TN; ++mm) {
      float val = 0.5f * (L[t * 64 + r * 8 + mm] + L[t * 64 + mm * 8 + r]);
      ws[WS_C2 + t * 64 + r * 8 + mm] = val;
      q += val * val;
    }
    ws[WS_CC + tid] = 0.125f * q;
  } else {
    const int row = tid - 128;
    const float4* tf = (const float4*)(TF + (size_t)row * F_DIM);
    float s = 0.f;
#pragma unroll
    for (int c = 0; c < 32; ++c) {
      float4 v = tf[c];
      s += v.x * v.x + v.y * v.y + v.z * v.z + v.w * v.w;
    }
    ws[WS_TFSQ + row] = s;
  }
  float4* tft = (float4*)(ws + WS_TFT);
  const float4* tf4 = (const float4*)TF;
  for (int i = tid; i < 4096; i += 256) {
    int row = i >> 5, c = i & 31;
    tft[c * 128 + row] = tf4[i];
  }
}

// ---------------- G2 pass: G2[n][tm] = (|x_n|^2 - 2 x_n.TF_tm)/256 ----------
__global__ __launch_bounds__(256) void gemm_g2_kernel(
    const float* __restrict__ x, const float* __restrict__ ws,
    float* __restrict__ G2) {
  __shared__ float xrow[2][128];
  const int tid = threadIdx.x;
  const int n0 = blockIdx.x * 2;

  if (tid < 64) {
    int nl = tid >> 5, c4 = tid & 31;
    float4 v = ((const float4*)(x + (size_t)(n0 + nl) * F_DIM))[c4];
    *(float4*)&xrow[nl][c4 * 4] = v;
  }
  __syncthreads();

  const int nl = tid >> 7;        // node within block
  const int sub = tid & 127;      // output column (template-row)
  const float4* tft = (const float4*)(ws + WS_TFT);

  v2f dot = {0.f, 0.f}, xq = {0.f, 0.f};
#pragma unroll 4
  for (int c = 0; c < 32; ++c) {
    float4 tf = tft[c * 128 + sub];            // coalesced 1KB/wave, L2-hot
    float4 xv = *(const float4*)&xrow[nl][c * 4];  // LDS broadcast
    v2f xa = {xv.x, xv.y}, xb = {xv.z, xv.w};
    v2f ta = {tf.x, tf.y}, tb = {tf.z, tf.w};
    dot = xa * ta + dot;
    dot = xb * tb + dot;
    xq = xa * xa + xq;
    xq = xb * xb + xq;
  }
  float d = dot.x + dot.y, q = xq.x + xq.y;
  G2[(size_t)(n0 + nl) * 128 + sub] = (q - 2.f * d) * (1.f / 256.f);
}

// ---------------- sink: G2 gather + Sinkhorn (validated R13/R14) ------------
__global__ __launch_bounds__(256) void sink_kernel(
    const float* __restrict__ G2, const int* __restrict__ edge,
    const float* __restrict__ ws, const float* __restrict__ W,
    const float* __restrict__ bias, float* __restrict__ out) {
  __shared__ float g2s[4][NL][128];   // staged G2 rows (broadcast/2-way reads)
  __shared__ int nas[4][NL];
  __shared__ float C2s[TT * 68];
  __shared__ float sc[4][TT * 20];
  __shared__ float fgw_s[4][TT];

  const int tid = threadIdx.x;
  const int node0 = blockIdx.x * 4;
  const int* dst = edge + E_EDGES;

  for (int i = tid; i < 1024; i += 256) {
    int t = i >> 6, rest = i & 63;
    C2s[t * 68 + rest] = ws[WS_C2 + i];
  }
  __syncthreads();  // C2s is cross-wave; everything below is per-wave

  const int lane = tid & 63;
  const int w = tid >> 6;
  const int node = node0 + w;
  const int t = lane >> 2;   // template
  const int p = lane & 3;    // column pair: m = {2p, 2p+1}

  // ---- per-wave: neighbor list -> LDS (wave-internal ordering only) ----
  if (lane < NL)
    nas[w][lane] = (lane == 0) ? node : dst[node * KN + (lane - 1)];

  // ---- per-wave: stage 17 G2 rows (coalesced 256B per half-wave) ----
  {
    const int half = lane >> 5, c4 = lane & 31;
#pragma unroll
    for (int i = 0; i < 9; ++i) {
      const int row = 2 * i + half;
      if (row < NL) {
        const int rna = nas[w][row];
        float4 v = ((const float4*)(G2 + (size_t)rna * 128))[c4];
        *(float4*)&g2s[w][row][c4 * 4] = v;
      }
    }
  }

  // ---- Mh from staged G2: Mh[a] = g2pair + (tfsq/256 + base) ----
  const v2f tfsq2 = *(const v2f*)(ws + WS_TFSQ + 2 * lane);
  const v2f cc2 = *(const v2f*)(ws + WS_CC + 2 * lane);
  const v2f K20 = tfsq2 * (1.f / 256.f) +
                  0.5f * ((v2f){16.f / 17.f, 16.f / 17.f} + cc2);
  const v2f K2a = tfsq2 * (1.f / 256.f) +
                  0.5f * ((v2f){1.f / 17.f, 1.f / 17.f} + cc2);

  v2f EM2[NL], Mh02, mnr;
  {
    const float* gb = &g2s[w][0][t * 8 + 2 * p];
    v2f m0 = *(const v2f*)(gb) + K20;
    Mh02 = m0;
    EM2[0] = exp2v(-m0 * CEXP);
    v2f m1 = *(const v2f*)(&g2s[w][1][t * 8 + 2 * p]) + K2a;
    mnr = m1;
    EM2[1] = exp2v(-m1 * CEXP);
#pragma unroll
    for (int a = 2; a < NL; ++a) {
      v2f mv = *(const v2f*)(&g2s[w][a][t * 8 + 2 * p]) + K2a;
      mnr = minv(mnr, mv);
      EM2[a] = exp2v(-mv * CEXP);
    }
  }

  // ---- Sinkhorn (byte-identical validated R13/R14) ----
  v2f PK2[NL];
#pragma unroll
  for (int a = 0; a < NL; ++a) PK2[a] = (v2f){1.f / 136.f, 1.f / 136.f};

  float r[NL], U[NL];
  float* myc = &sc[w][t * 20];
  v2f A02, A12;

#pragma unroll 1
  for (int it = 0; it < 5; ++it) {
    v2f sP2 = PK2[1];
#pragma unroll
    for (int a = 2; a < NL; ++a) sP2 += PK2[a];
    *(v2f*)&myc[2 * p] = sP2;
    *(v2f*)&myc[8 + 2 * p] = PK2[0];
    float4 s01 = *(const float4*)&myc[0];
    float4 s23 = *(const float4*)&myc[4];
    float4 p01 = *(const float4*)&myc[8];
    float4 p23 = *(const float4*)&myc[12];
    {
      const float* c2b = &C2s[t * 68 + 2 * p];
      v2f c0 = *(const v2f*)(c2b), c1 = *(const v2f*)(c2b + 8),
          c2 = *(const v2f*)(c2b + 16), c3 = *(const v2f*)(c2b + 24),
          c4 = *(const v2f*)(c2b + 32), c5 = *(const v2f*)(c2b + 40),
          c6 = *(const v2f*)(c2b + 48), c7 = *(const v2f*)(c2b + 56);
      A02 = c0 * s01.x + c1 * s01.y;
      A02 += c2 * s01.z + c3 * s01.w;
      A02 += c4 * s23.x + c5 * s23.y;
      A02 += c6 * s23.z + c7 * s23.w;
      A12 = c0 * p01.x + c1 * p01.y;
      A12 += c2 * p01.z + c3 * p01.w;
      A12 += c4 * p23.x + c5 * p23.y;
      A12 += c6 * p23.z + c7 * p23.w;
    }

    v2f g0 = Mh02 - A02, g1 = mnr - A12;
    float gmin = fminf(fminf(g0.x, g0.y), fminf(g1.x, g1.y));
    gmin = q4min(gmin);

    v2f EA0 = exp2v((A02 + gmin) * CEXP);
    v2f EA1 = exp2v((A12 + gmin) * CEXP);
    PK2[0] = PK2[0] * EM2[0] * EA0;
#pragma unroll
    for (int a = 1; a < NL; ++a) PK2[a] = PK2[a] * EM2[a] * EA1;

    v2f V;
    {
#pragma unroll
      for (int a = 0; a < NL; ++a) {
        float rr = PK2[a].x + PK2[a].y;
        r[a] = q4sum(rr);
      }
      minv17(r, U);
      v2f s2 = PK2[0] * U[0];
#pragma unroll
      for (int a = 1; a < NL; ++a) s2 += PK2[a] * U[a];
      V = 2.125f * rcpv(s2);
    }
#pragma unroll 1
    for (int si = 1; si < 10; ++si) {
#pragma unroll
      for (int a = 0; a < NL; ++a) {
        v2f pr = PK2[a] * V;
        r[a] = q4sum(pr.x + pr.y);
      }
      minv17(r, U);
      v2f s2 = PK2[0] * U[0];
#pragma unroll
      for (int a = 1; a < NL; ++a) s2 += PK2[a] * U[a];
      V = 2.125f * rcpv(s2);
    }
    const v2f hV = V * (1.f / 17.f);
#pragma unroll
    for (int a = 0; a < NL; ++a) PK2[a] = PK2[a] * U[a] * hV;
  }

  // ---- final fgw ----
  {
    v2f sP2 = PK2[1];
#pragma unroll
    for (int a = 2; a < NL; ++a) sP2 += PK2[a];
    *(v2f*)&myc[2 * p] = sP2;
    *(v2f*)&myc[8 + 2 * p] = PK2[0];
    float4 s01 = *(const float4*)&myc[0];
    float4 s23 = *(const float4*)&myc[4];
    float4 p01 = *(const float4*)&myc[8];
    float4 p23 = *(const float4*)&myc[12];
    const float* c2b = &C2s[t * 68 + 2 * p];
    v2f c0 = *(const v2f*)(c2b), c1 = *(const v2f*)(c2b + 8),
        c2 = *(const v2f*)(c2b + 16), c3 = *(const v2f*)(c2b + 24),
        c4 = *(const v2f*)(c2b + 32), c5 = *(const v2f*)(c2b + 40),
        c6 = *(const v2f*)(c2b + 48), c7 = *(const v2f*)(c2b + 56);
    A02 = c0 * s01.x + c1 * s01.y;
    A02 += c2 * s01.z + c3 * s01.w;
    A02 += c4 * s23.x + c5 * s23.y;
    A02 += c6 * s23.z + c7 * s23.w;
    A12 = c0 * p01.x + c1 * p01.y;
    A12 += c2 * p01.z + c3 * p01.w;
    A12 += c4 * p23.x + c5 * p23.y;
    A12 += c6 * p23.z + c7 * p23.w;
  }
  v2f acc2 = {0.f, 0.f};
#pragma unroll
  for (int a = 0; a < NL; ++a) {
    v2f mh2;
    mh2.x = -__log2f(EM2[a].x) * ICEXP;
    mh2.y = -__log2f(EM2[a].y) * ICEXP;
    acc2 += (mh2 - ((a == 0) ? A02 : A12)) * PK2[a];
  }
  float acc = q4sum(acc2.x + acc2.y);  // fgw(node,t), replicated in quad

  if (p == 0) fgw_s[w][t] = acc;
  // intra-wave LDS RAW: program order within a wave (validated R13/R14)
  if (lane < 8) {
    float o = bias[lane];
#pragma unroll
    for (int t2 = 0; t2 < TT; ++t2) o += fgw_s[w][t2] * W[t2 * 8 + lane];
    out[node * 8 + lane] = o;
  }
}

extern "C" void kernel_launch(void* const* d_in, const int* in_sizes, int n_in,
                              void* d_out, int out_size, void* d_ws, size_t ws_size,
                              hipStream_t stream) {
  const float* x = (const float*)d_in[0];
  const int* edge = (const int*)d_in[1];
  const float* L = (const float*)d_in[2];
  const float* TF = (const float*)d_in[3];
  const float* W = (const float*)d_in[4];
  const float* bias = (const float*)d_in[5];
  float* out = (float*)d_out;
  float* ws = (float*)d_ws;
  (void)in_sizes; (void)n_in; (void)ws_size; (void)out_size;

  float* G2 = ws + WS_G2;
  setup_kernel<<<1, 256, 0, stream>>>(L, TF, ws);
  gemm_g2_kernel<<<N_NODES / 2, 256, 0, stream>>>(x, ws, G2);
  sink_kernel<<<N_NODES / 4, 256, 0, stream>>>(G2, edge, ws, W, bias, out);
}

// Round 17
// 248.100 us; speedup vs baseline: 1.5514x; 1.0113x over previous
//
#include <hip/hip_runtime.h>

// OT_GNN_layer — round 17: drop sink's LDS staging (the wave's G2-row demand
// IS one coalesced 512B load), lifting the LDS occupancy cap (45KB -> ~10KB,
// 3 -> ~7 blocks/CU). N,F,T,Tn,C = 10000,128,16,8,8 ; E=160000 ; hardcoded.
// Pipeline: setup (tables+tft) | gemm_g2 (G2[n][tm], L2-resident 5.12MB) |
// sink (direct v2f G2 gather + validated R13-R16 Sinkhorn).

#define F_DIM 128
#define KN 16
#define NL 17
#define TT 16
#define TN 8
#define N_NODES 10000
#define E_EDGES 160000
#define CEXP 7.2134752044448170f    // (1/EPS)*log2(e), EPS=0.2
#define ICEXP 0.138629436111989062f // 1/CEXP

// ws float offsets
#define WS_TFSQ 0
#define WS_CC 128
#define WS_C2 256
#define WS_TFT 1280               // float4 tft[c*128+row], 4096 entries
#define WS_G2 17664               // 10000*128 floats = 5.12 MB

typedef float v2f __attribute__((ext_vector_type(2)));

template <int CTRL>
__device__ __forceinline__ float dppmov(float x) {
  return __int_as_float(__builtin_amdgcn_update_dpp(
      0, __float_as_int(x), CTRL, 0xF, 0xF, true));
}
__device__ __forceinline__ float q4sum(float x) {
  x += dppmov<0xB1>(x);
  x += dppmov<0x4E>(x);
  return x;
}
__device__ __forceinline__ float q4min(float x) {
  x = fminf(x, dppmov<0xB1>(x));
  x = fminf(x, dppmov<0x4E>(x));
  return x;
}
__device__ __forceinline__ v2f exp2v(v2f a) {
  v2f r; r.x = exp2f(a.x); r.y = exp2f(a.y); return r;
}
__device__ __forceinline__ v2f rcpv(v2f a) {
  v2f r;
  r.x = __builtin_amdgcn_rcpf(a.x);
  r.y = __builtin_amdgcn_rcpf(a.y);
  return r;
}
__device__ __forceinline__ v2f minv(v2f a, v2f b) {
  v2f r; r.x = fminf(a.x, b.x); r.y = fminf(a.y, b.y); return r;
}

// batched reciprocal of 17 positive values: 4 rcp + ~39 mul (validated R11)
__device__ __forceinline__ void minv17(const float r[NL], float U[NL]) {
  {
    float p1 = r[0] * r[1], p2 = p1 * r[2], p3 = p2 * r[3];
    float R = __builtin_amdgcn_rcpf(p3);
    U[3] = R * p2; R *= r[3];
    U[2] = R * p1; R *= r[2];
    U[1] = R * r[0];
    U[0] = R * r[1];
  }
  {
    float p1 = r[4] * r[5], p2 = p1 * r[6], p3 = p2 * r[7];
    float R = __builtin_amdgcn_rcpf(p3);
    U[7] = R * p2; R *= r[7];
    U[6] = R * p1; R *= r[6];
    U[5] = R * r[4];
    U[4] = R * r[5];
  }
  {
    float p1 = r[8] * r[9], p2 = p1 * r[10], p3 = p2 * r[11];
    float R = __builtin_amdgcn_rcpf(p3);
    U[11] = R * p2; R *= r[11];
    U[10] = R * p1; R *= r[10];
    U[9] = R * r[8];
    U[8] = R * r[9];
  }
  {
    float p1 = r[12] * r[13], p2 = p1 * r[14], p3 = p2 * r[15],
          p4 = p3 * r[16];
    float R = __builtin_amdgcn_rcpf(p4);
    U[16] = R * p3; R *= r[16];
    U[15] = R * p2; R *= r[15];
    U[14] = R * p1; R *= r[14];
    U[13] = R * r[12];
    U[12] = R * r[13];
  }
}

// ---------------- setup: tables + col-major TF ----------------
__global__ __launch_bounds__(256) void setup_kernel(
    const float* __restrict__ L, const float* __restrict__ TF,
    float* __restrict__ ws) {
  const int tid = threadIdx.x;
  if (tid < 128) {
    const int t = tid >> 3, r = tid & 7;
    float q = 0.f;
#pragma unroll
    for (int mm = 0; mm < TN; ++mm) {
      float val = 0.5f * (L[t * 64 + r * 8 + mm] + L[t * 64 + mm * 8 + r]);
      ws[WS_C2 + t * 64 + r * 8 + mm] = val;
      q += val * val;
    }
    ws[WS_CC + tid] = 0.125f * q;
  } else {
    const int row = tid - 128;
    const float4* tf = (const float4*)(TF + (size_t)row * F_DIM);
    float s = 0.f;
#pragma unroll
    for (int c = 0; c < 32; ++c) {
      float4 v = tf[c];
      s += v.x * v.x + v.y * v.y + v.z * v.z + v.w * v.w;
    }
    ws[WS_TFSQ + row] = s;
  }
  float4* tft = (float4*)(ws + WS_TFT);
  const float4* tf4 = (const float4*)TF;
  for (int i = tid; i < 4096; i += 256) {
    int row = i >> 5, c = i & 31;
    tft[c * 128 + row] = tf4[i];
  }
}

// ---------------- G2 pass: G2[n][tm] = (|x_n|^2 - 2 x_n.TF_tm)/256 ----------
__global__ __launch_bounds__(256) void gemm_g2_kernel(
    const float* __restrict__ x, const float* __restrict__ ws,
    float* __restrict__ G2) {
  __shared__ float xrow[2][128];
  const int tid = threadIdx.x;
  const int n0 = blockIdx.x * 2;

  if (tid < 64) {
    int nl = tid >> 5, c4 = tid & 31;
    float4 v = ((const float4*)(x + (size_t)(n0 + nl) * F_DIM))[c4];
    *(float4*)&xrow[nl][c4 * 4] = v;
  }
  __syncthreads();

  const int nl = tid >> 7;
  const int sub = tid & 127;
  const float4* tft = (const float4*)(ws + WS_TFT);

  v2f dot = {0.f, 0.f}, xq = {0.f, 0.f};
#pragma unroll 4
  for (int c = 0; c < 32; ++c) {
    float4 tf = tft[c * 128 + sub];                // coalesced 1KB/wave
    float4 xv = *(const float4*)&xrow[nl][c * 4];  // LDS broadcast
    v2f xa = {xv.x, xv.y}, xb = {xv.z, xv.w};
    v2f ta = {tf.x, tf.y}, tb = {tf.z, tf.w};
    dot = xa * ta + dot;
    dot = xb * tb + dot;
    xq = xa * xa + xq;
    xq = xb * xb + xq;
  }
  float d = dot.x + dot.y, q = xq.x + xq.y;
  G2[(size_t)(n0 + nl) * 128 + sub] = (q - 2.f * d) * (1.f / 256.f);
}

// ---------------- sink: direct G2 gather + Sinkhorn ----------------
__global__ __launch_bounds__(256) void sink_kernel(
    const float* __restrict__ G2, const int* __restrict__ edge,
    const float* __restrict__ ws, const float* __restrict__ W,
    const float* __restrict__ bias, float* __restrict__ out) {
  __shared__ float C2s[TT * 68];
  __shared__ float sc[4][TT * 20];
  __shared__ float fgw_s[4][TT];

  const int tid = threadIdx.x;
  const int node0 = blockIdx.x * 4;
  const int* dst = edge + E_EDGES;

  for (int i = tid; i < 1024; i += 256) {
    int t = i >> 6, rest = i & 63;
    C2s[t * 68 + rest] = ws[WS_C2 + i];
  }
  __syncthreads();

  const int lane = tid & 63;
  const int w = tid >> 6;
  const int node = node0 + w;
  const int t = lane >> 2;   // template
  const int p = lane & 3;    // column pair: m = {2p, 2p+1}

  // ---- Mh via direct coalesced G2 gather (one 512B load per row) ----
  // For fixed row a: lanes cover offsets t*8+2p = 0..126 step 2 -> the wave
  // reads one contiguous 512B segment of G2[na[a]] (global_load_dwordx2).
  const int loff = t * 8 + 2 * p;
  const v2f tfsq2 = *(const v2f*)(ws + WS_TFSQ + 2 * lane);
  const v2f cc2 = *(const v2f*)(ws + WS_CC + 2 * lane);
  const v2f K20 = tfsq2 * (1.f / 256.f) +
                  0.5f * ((v2f){16.f / 17.f, 16.f / 17.f} + cc2);
  const v2f K2a = tfsq2 * (1.f / 256.f) +
                  0.5f * ((v2f){1.f / 17.f, 1.f / 17.f} + cc2);

  v2f EM2[NL], Mh02, mnr;
  {
    // neighbor ids are wave-uniform -> scalar loads (validated R9-R11)
    v2f m0 = *(const v2f*)(G2 + (size_t)node * 128 + loff) + K20;
    Mh02 = m0;
    EM2[0] = exp2v(-m0 * CEXP);
    {
      int na = dst[node * KN + 0];
      v2f m1 = *(const v2f*)(G2 + (size_t)na * 128 + loff) + K2a;
      mnr = m1;
      EM2[1] = exp2v(-m1 * CEXP);
    }
#pragma unroll
    for (int a = 2; a < NL; ++a) {
      int na = dst[node * KN + (a - 1)];
      v2f mv = *(const v2f*)(G2 + (size_t)na * 128 + loff) + K2a;
      mnr = minv(mnr, mv);
      EM2[a] = exp2v(-mv * CEXP);
    }
  }

  // ---- Sinkhorn (byte-identical validated R13-R16) ----
  v2f PK2[NL];
#pragma unroll
  for (int a = 0; a < NL; ++a) PK2[a] = (v2f){1.f / 136.f, 1.f / 136.f};

  float r[NL], U[NL];
  float* myc = &sc[w][t * 20];
  v2f A02, A12;

#pragma unroll 1
  for (int it = 0; it < 5; ++it) {
    v2f sP2 = PK2[1];
#pragma unroll
    for (int a = 2; a < NL; ++a) sP2 += PK2[a];
    *(v2f*)&myc[2 * p] = sP2;
    *(v2f*)&myc[8 + 2 * p] = PK2[0];
    float4 s01 = *(const float4*)&myc[0];
    float4 s23 = *(const float4*)&myc[4];
    float4 p01 = *(const float4*)&myc[8];
    float4 p23 = *(const float4*)&myc[12];
    {
      const float* c2b = &C2s[t * 68 + 2 * p];
      v2f c0 = *(const v2f*)(c2b), c1 = *(const v2f*)(c2b + 8),
          c2 = *(const v2f*)(c2b + 16), c3 = *(const v2f*)(c2b + 24),
          c4 = *(const v2f*)(c2b + 32), c5 = *(const v2f*)(c2b + 40),
          c6 = *(const v2f*)(c2b + 48), c7 = *(const v2f*)(c2b + 56);
      A02 = c0 * s01.x + c1 * s01.y;
      A02 += c2 * s01.z + c3 * s01.w;
      A02 += c4 * s23.x + c5 * s23.y;
      A02 += c6 * s23.z + c7 * s23.w;
      A12 = c0 * p01.x + c1 * p01.y;
      A12 += c2 * p01.z + c3 * p01.w;
      A12 += c4 * p23.x + c5 * p23.y;
      A12 += c6 * p23.z + c7 * p23.w;
    }

    v2f g0 = Mh02 - A02, g1 = mnr - A12;
    float gmin = fminf(fminf(g0.x, g0.y), fminf(g1.x, g1.y));
    gmin = q4min(gmin);

    v2f EA0 = exp2v((A02 + gmin) * CEXP);
    v2f EA1 = exp2v((A12 + gmin) * CEXP);
    PK2[0] = PK2[0] * EM2[0] * EA0;
#pragma unroll
    for (int a = 1; a < NL; ++a) PK2[a] = PK2[a] * EM2[a] * EA1;

    v2f V;
    {
#pragma unroll
      for (int a = 0; a < NL; ++a) {
        float rr = PK2[a].x + PK2[a].y;
        r[a] = q4sum(rr);
      }
      minv17(r, U);
      v2f s2 = PK2[0] * U[0];
#pragma unroll
      for (int a = 1; a < NL; ++a) s2 += PK2[a] * U[a];
      V = 2.125f * rcpv(s2);
    }
#pragma unroll 1
    for (int si = 1; si < 10; ++si) {
#pragma unroll
      for (int a = 0; a < NL; ++a) {
        v2f pr = PK2[a] * V;
        r[a] = q4sum(pr.x + pr.y);
      }
      minv17(r, U);
      v2f s2 = PK2[0] * U[0];
#pragma unroll
      for (int a = 1; a < NL; ++a) s2 += PK2[a] * U[a];
      V = 2.125f * rcpv(s2);
    }
    const v2f hV = V * (1.f / 17.f);
#pragma unroll
    for (int a = 0; a < NL; ++a) PK2[a] = PK2[a] * U[a] * hV;
  }

  // ---- final fgw ----
  {
    v2f sP2 = PK2[1];
#pragma unroll
    for (int a = 2; a < NL; ++a) sP2 += PK2[a];
    *(v2f*)&myc[2 * p] = sP2;
    *(v2f*)&myc[8 + 2 * p] = PK2[0];
    float4 s01 = *(const float4*)&myc[0];
    float4 s23 = *(const float4*)&myc[4];
    float4 p01 = *(const float4*)&myc[8];
    float4 p23 = *(const float4*)&myc[12];
    const float* c2b = &C2s[t * 68 + 2 * p];
    v2f c0 = *(const v2f*)(c2b), c1 = *(const v2f*)(c2b + 8),
        c2 = *(const v2f*)(c2b + 16), c3 = *(const v2f*)(c2b + 24),
        c4 = *(const v2f*)(c2b + 32), c5 = *(const v2f*)(c2b + 40),
        c6 = *(const v2f*)(c2b + 48), c7 = *(const v2f*)(c2b + 56);
    A02 = c0 * s01.x + c1 * s01.y;
    A02 += c2 * s01.z + c3 * s01.w;
    A02 += c4 * s23.x + c5 * s23.y;
    A02 += c6 * s23.z + c7 * s23.w;
    A12 = c0 * p01.x + c1 * p01.y;
    A12 += c2 * p01.z + c3 * p01.w;
    A12 += c4 * p23.x + c5 * p23.y;
    A12 += c6 * p23.z + c7 * p23.w;
  }
  v2f acc2 = {0.f, 0.f};
#pragma unroll
  for (int a = 0; a < NL; ++a) {
    v2f mh2;
    mh2.x = -__log2f(EM2[a].x) * ICEXP;
    mh2.y = -__log2f(EM2[a].y) * ICEXP;
    acc2 += (mh2 - ((a == 0) ? A02 : A12)) * PK2[a];
  }
  float acc = q4sum(acc2.x + acc2.y);  // fgw(node,t), replicated in quad

  if (p == 0) fgw_s[w][t] = acc;
  // intra-wave LDS RAW: program order within a wave (validated R13-R16)
  if (lane < 8) {
    float o = bias[lane];
#pragma unroll
    for (int t2 = 0; t2 < TT; ++t2) o += fgw_s[w][t2] * W[t2 * 8 + lane];
    out[node * 8 + lane] = o;
  }
}

extern "C" void kernel_launch(void* const* d_in, const int* in_sizes, int n_in,
                              void* d_out, int out_size, void* d_ws, size_t ws_size,
                              hipStream_t stream) {
  const float* x = (const float*)d_in[0];
  const int* edge = (const int*)d_in[1];
  const float* L = (const float*)d_in[2];
  const float* TF = (const float*)d_in[3];
  const float* W = (const float*)d_in[4];
  const float* bias = (const float*)d_in[5];
  float* out = (float*)d_out;
  float* ws = (float*)d_ws;
  (void)in_sizes; (void)n_in; (void)ws_size; (void)out_size;

  float* G2 = ws + WS_G2;
  setup_kernel<<<1, 256, 0, stream>>>(L, TF, ws);
  gemm_g2_kernel<<<N_NODES / 2, 256, 0, stream>>>(x, ws, G2);
  sink_kernel<<<N_NODES / 4, 256, 0, stream>>>(G2, edge, ws, W, bias, out);
}